// Round 6
// baseline (176.716 us; speedup 1.0000x reference)
//
#include <hip/hip_runtime.h>
#include <stdint.h>

typedef __attribute__((ext_vector_type(4))) float f32x4;
typedef __attribute__((ext_vector_type(8))) __bf16 bf16x8;
typedef __attribute__((ext_vector_type(8))) unsigned short u16x8;

__device__ __forceinline__ unsigned short f2b(float f) {
  unsigned u = __float_as_uint(f);
  u += 0x7FFFu + ((u >> 16) & 1u);   // RNE
  return (unsigned short)(u >> 16);
}

__device__ __forceinline__ void gload_lds16(const void* g, void* l) {
  typedef __attribute__((address_space(1))) void GV1;
  typedef __attribute__((address_space(3))) void LV3;
  __builtin_amdgcn_global_load_lds((GV1*)(void*)g, (LV3*)l, 16, 0, 0);
}

// ---------------- conversion kernels ----------------
__global__ __launch_bounds__(256) void convert_f32_bf16(const float* __restrict__ in,
                                                        unsigned short* __restrict__ out, int n) {
  int i = (blockIdx.x * 256 + threadIdx.x) * 8;
  if (i >= n) return;
  float4 a = *(const float4*)(in + i);
  float4 b = *(const float4*)(in + i + 4);
  u16x8 r;
  r[0] = f2b(a.x); r[1] = f2b(a.y); r[2] = f2b(a.z); r[3] = f2b(a.w);
  r[4] = f2b(b.x); r[5] = f2b(b.y); r[6] = f2b(b.z); r[7] = f2b(b.w);
  *(u16x8*)(out + i) = r;
}

// W [K][N] f32 -> Wt [N][K] bf16
__global__ __launch_bounds__(256) void transpose_f32_bf16(const float* __restrict__ W,
                                                          unsigned short* __restrict__ Wt,
                                                          int K, int N) {
  __shared__ unsigned short tile[32][33];
  int n0 = blockIdx.x * 32, k0 = blockIdx.y * 32;
  int tx = threadIdx.x, ty = threadIdx.y;  // 32 x 8
  #pragma unroll
  for (int j = 0; j < 32; j += 8)
    tile[ty + j][tx] = f2b(W[(size_t)(k0 + ty + j) * N + n0 + tx]);
  __syncthreads();
  #pragma unroll
  for (int j = 0; j < 32; j += 8)
    Wt[(size_t)(n0 + ty + j) * K + k0 + tx] = tile[tx][ty + j];
}

// ---------------- GEMM: C[M][N] = A[M][K] * Bt[N][K]^T + bias ----------------
template <bool OUT_BF16>
__global__ __launch_bounds__(256) void gemm_bt(const unsigned short* __restrict__ A,
                                               const unsigned short* __restrict__ Bt,
                                               const float* __restrict__ bias,
                                               void* __restrict__ Cout,
                                               int M, int N, int K) {
  __shared__ unsigned short As[128 * 64];
  __shared__ unsigned short Bs[128 * 64];
  const int m0 = blockIdx.x * 128, n0 = blockIdx.y * 128;
  const int tid = threadIdx.x;
  const int w = tid >> 6, l = tid & 63;
  const int wm = w >> 1, wn = w & 1;
  const int c = l & 15, g = l >> 4;
  f32x4 acc[4][4] = {};
  for (int k0 = 0; k0 < K; k0 += 64) {
    #pragma unroll
    for (int i = 0; i < 4; ++i) {
      int rb = w * 32 + i * 8;
      gload_lds16(A + (size_t)(m0 + rb + (l >> 3)) * K + k0 + (l & 7) * 8, &As[rb * 64]);
      gload_lds16(Bt + (size_t)(n0 + rb + (l >> 3)) * K + k0 + (l & 7) * 8, &Bs[rb * 64]);
    }
    __syncthreads();
    #pragma unroll
    for (int ks = 0; ks < 2; ++ks) {
      bf16x8 af[4], bf[4];
      #pragma unroll
      for (int mi = 0; mi < 4; ++mi)
        af[mi] = *(const bf16x8*)&As[(wm * 64 + mi * 16 + c) * 64 + ks * 32 + g * 8];
      #pragma unroll
      for (int ni = 0; ni < 4; ++ni)
        bf[ni] = *(const bf16x8*)&Bs[(wn * 64 + ni * 16 + c) * 64 + ks * 32 + g * 8];
      #pragma unroll
      for (int mi = 0; mi < 4; ++mi)
        #pragma unroll
        for (int ni = 0; ni < 4; ++ni)
          acc[mi][ni] = __builtin_amdgcn_mfma_f32_16x16x32_bf16(af[mi], bf[ni], acc[mi][ni], 0, 0, 0);
    }
    __syncthreads();
  }
  #pragma unroll
  for (int mi = 0; mi < 4; ++mi) {
    #pragma unroll
    for (int ni = 0; ni < 4; ++ni) {
      int colg = n0 + wn * 64 + ni * 16 + c;
      float bv = bias[colg];
      #pragma unroll
      for (int r = 0; r < 4; ++r) {
        int rowg = m0 + wm * 64 + mi * 16 + 4 * g + r;
        float v = acc[mi][ni][r] + bv;
        if (OUT_BF16)
          ((unsigned short*)Cout)[(size_t)rowg * N + colg] = f2b(v);
        else
          ((float*)Cout)[(size_t)rowg * N + colg] = v;
      }
    }
  }
}

// ---------------- causal flash attention ----------------
// qkv [4096][3072] bf16; out [4096][1024] bf16.
// 1024 blocks x 512 threads (8 waves). Block owns one 64-row q-tile.
// TWO WAVE-GROUPS split the kv-range (group g takes tiles t = 2i+g): per-block
// critical path halves (max 16 iters), each group has its own K/V dbuf, and
// the two partial softmax states merge in-block at the end via LDS.
// 1024 blocks on 512 resident slots (80KB LDS -> 2 blocks/CU) -> refill queue
// absorbs tail imbalance under the hardware's ACTUAL dispatch order (R4 lesson:
// never assume a dispatch->CU map). qt = 31-bid/32 heavy-first (R3 proven),
// bh = bid&31 for XCD/L2 locality (R1: FETCH 55->12MB).
__global__ __launch_bounds__(512) void attn_kernel(const unsigned short* __restrict__ qkv,
                                                   unsigned short* __restrict__ out) {
  __shared__ unsigned short K_lds[2][2][64 * 64];  // [grp][buf][kv][d], swizzled (32KB)
  __shared__ unsigned short V_lds[2][2][64 * 64];  // [grp][buf] V^T [d][kv], swizzled (32KB)
  __shared__ unsigned short P_lds[8][16 * 64];     // per-wave [16 q][64 kv], swizzled (16KB)
  const int bid = blockIdx.x;
  const int qt = 31 - (bid >> 5);                  // heavy-first
  const int bh = bid & 31;
  const int b = bh >> 4, h = bh & 15;
  const int tid = threadIdx.x, w = tid >> 6, l = tid & 63;
  const int grp = w >> 2, wl = w & 3;              // wave-group, wave-in-group
  const int c = l & 15, g = l >> 4;
  const size_t row0 = (size_t)b * 2048;
  const int lt = tid & 255;                        // thread index within group
  const int vp = lt & 31, vcb = lt >> 5;           // V-stage: kv-pair, d-chunk
  const float SCL = 0.18033688f;                   // 0.125 * log2(e): exp2 domain
  char* Pb = (char*)&P_lds[w][0];

  const int q0 = qt * 64;
  const int q0w = q0 + wl * 16;                    // this wave's 16 q-rows
  const int nt = qt + 1;                           // kv tiles total
  const int np = (nt + 1) >> 1;                    // pair-iterations (collective)

  // Q fragments: A-frag m=c, k=d=ks*32+8g+e (both groups load the same rows)
  bf16x8 qf[2];
  #pragma unroll
  for (int ks = 0; ks < 2; ++ks)
    qf[ks] = *(const bf16x8*)(qkv + (row0 + q0w + c) * 3072 + h * 64 + ks * 32 + g * 8);

  f32x4 acc[4] = {};
  float mstate[4], lstate[4];   // m: raw-score group max (uniform in 16-lane grp); l: per-lane partials
  #pragma unroll
  for (int r = 0; r < 4; ++r) { mstate[r] = -1e30f; lstate[r] = 0.f; }

  // ---- prologue: group g stages its tile t=g into buf 0 (skip if t>=nt)
  if (grp < nt) {
    #pragma unroll
    for (int i = 0; i < 2; ++i) {
      int rb = wl * 16 + i * 8;
      int row = rb + (l >> 3);
      int ch = (l & 7) ^ (row & 7);                // pre-swizzled source (m173)
      gload_lds16(qkv + (row0 + grp * 64 + row) * 3072 + 1024 + h * 64 + ch * 8,
                  &K_lds[grp][0][rb * 64]);
    }
    size_t tr = row0 + grp * 64 + 2 * vp;
    u16x8 v0 = *(const u16x8*)(qkv + tr * 3072 + 2048 + h * 64 + vcb * 8);
    u16x8 v1 = *(const u16x8*)(qkv + (tr + 1) * 3072 + 2048 + h * 64 + vcb * 8);
    char* Vb = (char*)&V_lds[grp][0][0];
    #pragma unroll
    for (int jj = 0; jj < 8; ++jj) {
      int d = vcb * 8 + jj;
      int off = d * 128 + ((4 * vp) ^ ((d & 7) << 4));
      *(unsigned int*)(Vb + off) = (unsigned int)v0[jj] | ((unsigned int)v1[jj] << 16);
    }
  }
  __syncthreads();

  for (int i = 0; i < np; ++i) {
    const int cur = i & 1;
    const int t = 2 * i + grp;                     // this group's tile
    const int tn = t + 2;                          // next own tile
    const bool pre = (tn < nt);
    u16x8 v0n, v1n;
    if (pre) {  // issue next own-tile loads BEFORE compute (2-phase pipeline)
      #pragma unroll
      for (int ii = 0; ii < 2; ++ii) {
        int rb = wl * 16 + ii * 8;
        int row = rb + (l >> 3);
        int ch = (l & 7) ^ (row & 7);
        gload_lds16(qkv + (row0 + tn * 64 + row) * 3072 + 1024 + h * 64 + ch * 8,
                    &K_lds[grp][cur ^ 1][rb * 64]);
      }
      size_t tr = row0 + tn * 64 + 2 * vp;
      v0n = *(const u16x8*)(qkv + tr * 3072 + 2048 + h * 64 + vcb * 8);
      v1n = *(const u16x8*)(qkv + (tr + 1) * 3072 + 2048 + h * 64 + vcb * 8);
    }
    if (t < nt) {
      const int kv0 = t * 64;
      const char* Kb = (const char*)&K_lds[grp][cur][0];
      const char* Vb = (const char*)&V_lds[grp][cur][0];
      // ---- S = Q K^T (raw scores)
      f32x4 s[4] = {};
      #pragma unroll
      for (int ks = 0; ks < 2; ++ks) {
        bf16x8 kf[4];
        #pragma unroll
        for (int nk = 0; nk < 4; ++nk) {
          int row = nk * 16 + c;
          kf[nk] = *(const bf16x8*)(Kb + row * 128 + ((ks * 64 + g * 16) ^ ((row & 7) << 4)));
        }
        __builtin_amdgcn_s_setprio(1);
        #pragma unroll
        for (int nk = 0; nk < 4; ++nk)
          s[nk] = __builtin_amdgcn_mfma_f32_16x16x32_bf16(qf[ks], kf[nk], s[nk], 0, 0, 0);
        __builtin_amdgcn_s_setprio(0);
      }
      // ---- causal mask only on the global diagonal tile
      if (t == nt - 1) {
        #pragma unroll
        for (int nk = 0; nk < 4; ++nk)
          #pragma unroll
          for (int r = 0; r < 4; ++r) {
            int rowg = q0w + 4 * g + r;
            int colg = kv0 + nk * 16 + c;
            if (colg > rowg) s[nk][r] = -1e30f;
          }
      }
      // ---- online softmax: row-max reduce, alpha==1 fast path, per-lane l-partials
      float mx[4];
      #pragma unroll
      for (int r = 0; r < 4; ++r) {
        float m0 = fmaxf(fmaxf(s[0][r], s[1][r]), fmaxf(s[2][r], s[3][r]));
        m0 = fmaxf(m0, __shfl_xor(m0, 1));
        m0 = fmaxf(m0, __shfl_xor(m0, 2));
        m0 = fmaxf(m0, __shfl_xor(m0, 4));
        m0 = fmaxf(m0, __shfl_xor(m0, 8));
        mx[r] = m0;
      }
      bool nogrow = (mx[0] <= mstate[0]) & (mx[1] <= mstate[1]) &
                    (mx[2] <= mstate[2]) & (mx[3] <= mstate[3]);
      if (!__all(nogrow)) {
        #pragma unroll
        for (int r = 0; r < 4; ++r) {
          float mold = mstate[r];
          float mnew = fmaxf(mold, mx[r]);
          float alpha = exp2f((mold - mnew) * SCL);
          mstate[r] = mnew;
          lstate[r] *= alpha;
          #pragma unroll
          for (int nd = 0; nd < 4; ++nd) acc[nd][r] *= alpha;
        }
      }
      #pragma unroll
      for (int r = 0; r < 4; ++r) {
        float ms = mstate[r] * SCL;
        float p0 = exp2f(fmaf(s[0][r], SCL, -ms));
        float p1 = exp2f(fmaf(s[1][r], SCL, -ms));
        float p2 = exp2f(fmaf(s[2][r], SCL, -ms));
        float p3 = exp2f(fmaf(s[3][r], SCL, -ms));
        s[0][r] = p0; s[1][r] = p1; s[2][r] = p2; s[3][r] = p3;
        lstate[r] += (p0 + p1) + (p2 + p3);
      }
      // ---- P -> LDS (bf16, swizzled; per-wave buffer)
      #pragma unroll
      for (int nk = 0; nk < 4; ++nk)
        #pragma unroll
        for (int r = 0; r < 4; ++r) {
          int row = 4 * g + r;
          int off = row * 128 + (((nk * 16 + c) * 2) ^ ((row & 7) << 4));
          *(unsigned short*)(Pb + off) = f2b(s[nk][r]);
        }
      // ---- O += P V
      #pragma unroll
      for (int ks = 0; ks < 2; ++ks) {
        bf16x8 pf, vf[4];
        pf = *(const bf16x8*)(Pb + c * 128 + ((ks * 64 + g * 16) ^ ((c & 7) << 4)));
        #pragma unroll
        for (int nd = 0; nd < 4; ++nd) {
          int row = nd * 16 + c;
          vf[nd] = *(const bf16x8*)(Vb + row * 128 + ((ks * 64 + g * 16) ^ ((row & 7) << 4)));
        }
        __builtin_amdgcn_s_setprio(1);
        #pragma unroll
        for (int nd = 0; nd < 4; ++nd)
          acc[nd] = __builtin_amdgcn_mfma_f32_16x16x32_bf16(pf, vf[nd], acc[nd], 0, 0, 0);
        __builtin_amdgcn_s_setprio(0);
      }
    }
    if (pre) {  // write prefetched V into next buffer (vmcnt wait lands here)
      char* Vbn = (char*)&V_lds[grp][cur ^ 1][0];
      #pragma unroll
      for (int jj = 0; jj < 8; ++jj) {
        int d = vcb * 8 + jj;
        int off = d * 128 + ((4 * vp) ^ ((d & 7) << 4));
        *(unsigned int*)(Vbn + off) = (unsigned int)v0n[jj] | ((unsigned int)v1n[jj] << 16);
      }
    }
    __syncthreads();  // collective: both groups run np iterations
  }

  // ---- epilogue: reduce per-lane l partials within the 16-lane group
  float ls[4];
  #pragma unroll
  for (int r = 0; r < 4; ++r) {
    float v = lstate[r];
    v += __shfl_xor(v, 1);
    v += __shfl_xor(v, 2);
    v += __shfl_xor(v, 4);
    v += __shfl_xor(v, 8);
    ls[r] = v;
  }
  // ---- merge the two groups' partials (reuse dead P_lds for acc, K_lds for m/l)
  float* accb = (float*)P_lds;                     // 4096 floats: 4 slices of 1024
  float* mlb  = (float*)K_lds;                     // m,l transfer
  if (grp == 1) {
    #pragma unroll
    for (int nd = 0; nd < 4; ++nd)
      #pragma unroll
      for (int r = 0; r < 4; ++r)
        accb[wl * 1024 + (4 * g + r) * 64 + nd * 16 + c] = acc[nd][r];
    if (c == 0) {
      #pragma unroll
      for (int r = 0; r < 4; ++r) {
        mlb[wl * 32 + (4 * g + r) * 2 + 0] = mstate[r];
        mlb[wl * 32 + (4 * g + r) * 2 + 1] = ls[r];
      }
    }
  }
  __syncthreads();
  if (grp == 0) {
    #pragma unroll
    for (int r = 0; r < 4; ++r) {
      float mb = mlb[wl * 32 + (4 * g + r) * 2 + 0];
      float lb = mlb[wl * 32 + (4 * g + r) * 2 + 1];
      float ma = mstate[r];
      float mstar = fmaxf(ma, mb);
      float aa = exp2f((ma - mstar) * SCL);
      float ab = exp2f((mb - mstar) * SCL);
      float rinv = 1.0f / (ls[r] * aa + lb * ab);
      size_t trow = row0 + q0w + 4 * g + r;
      #pragma unroll
      for (int nd = 0; nd < 4; ++nd) {
        float ob = accb[wl * 1024 + (4 * g + r) * 64 + nd * 16 + c];
        out[trow * 1024 + h * 64 + nd * 16 + c] = f2b((acc[nd][r] * aa + ob * ab) * rinv);
      }
    }
  }
}

// ---------------- launch ----------------
extern "C" void kernel_launch(void* const* d_in, const int* in_sizes, int n_in,
                              void* d_out, int out_size, void* d_ws, size_t ws_size,
                              hipStream_t stream) {
  const float* x      = (const float*)d_in[0];
  const float* W_attn = (const float*)d_in[1];
  const float* b_attn = (const float*)d_in[2];
  const float* W_proj = (const float*)d_in[3];
  const float* b_proj = (const float*)d_in[4];
  float* out = (float*)d_out;

  char* ws = (char*)d_ws;
  unsigned short* x_bf     = (unsigned short*)(ws + 0);           //  8 MB [4096][1024]
  unsigned short* Wattn_t  = (unsigned short*)(ws + 8388608);     //  6 MB [3072][1024]
  unsigned short* Wproj_t  = (unsigned short*)(ws + 14680064);    //  2 MB [1024][1024]
  unsigned short* qkv      = (unsigned short*)(ws + 16777216);    // 24 MB [4096][3072]
  unsigned short* attn_out = (unsigned short*)(ws + 41943040);    //  8 MB [4096][1024]

  convert_f32_bf16<<<2048, 256, 0, stream>>>(x, x_bf, 4194304);
  transpose_f32_bf16<<<dim3(96, 32), dim3(32, 8), 0, stream>>>(W_attn, Wattn_t, 1024, 3072);
  transpose_f32_bf16<<<dim3(32, 32), dim3(32, 8), 0, stream>>>(W_proj, Wproj_t, 1024, 1024);

  gemm_bt<true><<<dim3(32, 24), 256, 0, stream>>>(x_bf, Wattn_t, b_attn, qkv, 4096, 3072, 1024);
  attn_kernel<<<1024, 512, 0, stream>>>(qkv, attn_out);
  gemm_bt<false><<<dim3(32, 8), 256, 0, stream>>>(attn_out, Wproj_t, b_proj, out, 4096, 1024, 1024);
}

// Round 7
// 163.955 us; speedup vs baseline: 1.0778x; 1.0778x over previous
//
#include <hip/hip_runtime.h>
#include <stdint.h>

typedef __attribute__((ext_vector_type(4))) float f32x4;
typedef __attribute__((ext_vector_type(8))) __bf16 bf16x8;
typedef __attribute__((ext_vector_type(8))) unsigned short u16x8;

__device__ __forceinline__ unsigned short f2b(float f) {
  unsigned u = __float_as_uint(f);
  u += 0x7FFFu + ((u >> 16) & 1u);   // RNE
  return (unsigned short)(u >> 16);
}
__device__ __forceinline__ float b2f(unsigned short s) {
  unsigned u = (unsigned)s << 16;
  return __uint_as_float(u);
}

__device__ __forceinline__ void gload_lds16(const void* g, void* l) {
  typedef __attribute__((address_space(1))) void GV1;
  typedef __attribute__((address_space(3))) void LV3;
  __builtin_amdgcn_global_load_lds((GV1*)(void*)g, (LV3*)l, 16, 0, 0);
}

// ---------------- conversion kernels ----------------
__global__ __launch_bounds__(256) void convert_f32_bf16(const float* __restrict__ in,
                                                        unsigned short* __restrict__ out, int n) {
  int i = (blockIdx.x * 256 + threadIdx.x) * 8;
  if (i >= n) return;
  float4 a = *(const float4*)(in + i);
  float4 b = *(const float4*)(in + i + 4);
  u16x8 r;
  r[0] = f2b(a.x); r[1] = f2b(a.y); r[2] = f2b(a.z); r[3] = f2b(a.w);
  r[4] = f2b(b.x); r[5] = f2b(b.y); r[6] = f2b(b.z); r[7] = f2b(b.w);
  *(u16x8*)(out + i) = r;
}

// W [K][N] f32 -> Wt [N][K] bf16
__global__ __launch_bounds__(256) void transpose_f32_bf16(const float* __restrict__ W,
                                                          unsigned short* __restrict__ Wt,
                                                          int K, int N) {
  __shared__ unsigned short tile[32][33];
  int n0 = blockIdx.x * 32, k0 = blockIdx.y * 32;
  int tx = threadIdx.x, ty = threadIdx.y;  // 32 x 8
  #pragma unroll
  for (int j = 0; j < 32; j += 8)
    tile[ty + j][tx] = f2b(W[(size_t)(k0 + ty + j) * N + n0 + tx]);
  __syncthreads();
  #pragma unroll
  for (int j = 0; j < 32; j += 8)
    Wt[(size_t)(n0 + ty + j) * K + k0 + tx] = tile[tx][ty + j];
}

// ---------------- GEMM: C[M][N] = A[M][K] * Bt[N][K]^T + bias ----------------
template <bool OUT_BF16>
__global__ __launch_bounds__(256) void gemm_bt(const unsigned short* __restrict__ A,
                                               const unsigned short* __restrict__ Bt,
                                               const float* __restrict__ bias,
                                               void* __restrict__ Cout,
                                               int M, int N, int K) {
  __shared__ unsigned short As[128 * 64];
  __shared__ unsigned short Bs[128 * 64];
  const int m0 = blockIdx.x * 128, n0 = blockIdx.y * 128;
  const int tid = threadIdx.x;
  const int w = tid >> 6, l = tid & 63;
  const int wm = w >> 1, wn = w & 1;
  const int c = l & 15, g = l >> 4;
  f32x4 acc[4][4] = {};
  for (int k0 = 0; k0 < K; k0 += 64) {
    #pragma unroll
    for (int i = 0; i < 4; ++i) {
      int rb = w * 32 + i * 8;
      gload_lds16(A + (size_t)(m0 + rb + (l >> 3)) * K + k0 + (l & 7) * 8, &As[rb * 64]);
      gload_lds16(Bt + (size_t)(n0 + rb + (l >> 3)) * K + k0 + (l & 7) * 8, &Bs[rb * 64]);
    }
    __syncthreads();
    #pragma unroll
    for (int ks = 0; ks < 2; ++ks) {
      bf16x8 af[4], bf[4];
      #pragma unroll
      for (int mi = 0; mi < 4; ++mi)
        af[mi] = *(const bf16x8*)&As[(wm * 64 + mi * 16 + c) * 64 + ks * 32 + g * 8];
      #pragma unroll
      for (int ni = 0; ni < 4; ++ni)
        bf[ni] = *(const bf16x8*)&Bs[(wn * 64 + ni * 16 + c) * 64 + ks * 32 + g * 8];
      #pragma unroll
      for (int mi = 0; mi < 4; ++mi)
        #pragma unroll
        for (int ni = 0; ni < 4; ++ni)
          acc[mi][ni] = __builtin_amdgcn_mfma_f32_16x16x32_bf16(af[mi], bf[ni], acc[mi][ni], 0, 0, 0);
    }
    __syncthreads();
  }
  #pragma unroll
  for (int mi = 0; mi < 4; ++mi) {
    #pragma unroll
    for (int ni = 0; ni < 4; ++ni) {
      int colg = n0 + wn * 64 + ni * 16 + c;
      float bv = bias[colg];
      #pragma unroll
      for (int r = 0; r < 4; ++r) {
        int rowg = m0 + wm * 64 + mi * 16 + 4 * g + r;
        float v = acc[mi][ni][r] + bv;
        if (OUT_BF16)
          ((unsigned short*)Cout)[(size_t)rowg * N + colg] = f2b(v);
        else
          ((float*)Cout)[(size_t)rowg * N + colg] = v;
      }
    }
  }
}

// ---------------- causal flash attention, SPLIT-KV ----------------
// qkv [4096][3072] bf16. Each block: one 64-row q-tile x ONE KV CHUNK of <=8
// kv-tiles (KVBLK=64). Writes UNNORMALIZED partial O (bf16) + per-row (m,l).
// Critical path capped at 8 tiles regardless of dispatch order (R1-R5 lesson:
// total ~= nt_max * 2.84us; balance tricks via dispatch assumptions all failed).
// Chunk map per bh (80 chunks): cid 0..31 -> ct0 of qt=cid; 32..55 -> ct1 of
// qt=cid-24; 56..71 -> ct2 of qt=cid-40; 72..79 -> ct3 of qt=cid-48.
// bh = bid&31 keeps XCD/L2 locality (R1: FETCH 55->12MB).
__global__ __launch_bounds__(256) void attn_kernel(const unsigned short* __restrict__ qkv,
                                                   unsigned short* __restrict__ partO,
                                                   float* __restrict__ partML) {
  __shared__ unsigned short K_lds[2][64 * 64];     // [kv][d], XOR-swizzled rows
  __shared__ unsigned short V_lds[2][64 * 64];     // V^T [d][kv], XOR-swizzled rows
  __shared__ unsigned short P_lds[4 * 16 * 64];    // per-wave [16 q][64 kv], swizzled
  const int bid = blockIdx.x;
  const int bh = bid & 31;
  const int cid = bid >> 5;
  int qt, ct;
  if (cid < 32)      { qt = cid;      ct = 0; }
  else if (cid < 56) { qt = cid - 24; ct = 1; }
  else if (cid < 72) { qt = cid - 40; ct = 2; }
  else               { qt = cid - 48; ct = 3; }
  const int t0 = ct * 8;                           // first kv tile of chunk
  const int ntl = min(qt + 1 - t0, 8);             // tiles in this chunk (1..8)
  const bool hasdiag = (t0 + ntl - 1) == qt;       // chunk contains the diagonal
  const int b = bh >> 4, h = bh & 15;
  const int tid = threadIdx.x, w = tid >> 6, l = tid & 63;
  const int c = l & 15, g = l >> 4;
  const size_t row0 = (size_t)b * 2048;
  const int vp = tid & 31, vcb = tid >> 5;         // V-stage: kv-pair, d-chunk
  const float SCL = 0.18033688f;                   // 0.125 * log2(e): exp2 domain
  char* Pb = (char*)&P_lds[w * 16 * 64];

  const int q0w = qt * 64 + w * 16;

  // Q fragments: A-frag m=c, k=d=ks*32+8g+e
  bf16x8 qf[2];
  #pragma unroll
  for (int ks = 0; ks < 2; ++ks)
    qf[ks] = *(const bf16x8*)(qkv + (row0 + q0w + c) * 3072 + h * 64 + ks * 32 + g * 8);

  f32x4 acc[4] = {};
  float mstate[4], lstate[4];   // m: raw-score row max (uniform in 16-lane grp); l: per-lane partials
  #pragma unroll
  for (int r = 0; r < 4; ++r) { mstate[r] = -1e30f; lstate[r] = 0.f; }

  // ---- prologue: stage kv-tile t0 into buffer 0
  {
    #pragma unroll
    for (int i = 0; i < 2; ++i) {
      int rb = w * 16 + i * 8;
      int row = rb + (l >> 3);
      int ch = (l & 7) ^ (row & 7);                // pre-swizzled source (m173)
      gload_lds16(qkv + (row0 + t0 * 64 + row) * 3072 + 1024 + h * 64 + ch * 8,
                  &K_lds[0][rb * 64]);
    }
    size_t tr = row0 + t0 * 64 + 2 * vp;
    u16x8 v0 = *(const u16x8*)(qkv + tr * 3072 + 2048 + h * 64 + vcb * 8);
    u16x8 v1 = *(const u16x8*)(qkv + (tr + 1) * 3072 + 2048 + h * 64 + vcb * 8);
    char* Vb = (char*)V_lds[0];
    #pragma unroll
    for (int jj = 0; jj < 8; ++jj) {
      int d = vcb * 8 + jj;
      int off = d * 128 + ((4 * vp) ^ ((d & 7) << 4));
      *(unsigned int*)(Vb + off) = (unsigned int)v0[jj] | ((unsigned int)v1[jj] << 16);
    }
  }
  __syncthreads();

  for (int lt = 0; lt < ntl; ++lt) {
    const int cur = lt & 1;
    const int kv0 = (t0 + lt) * 64;
    const bool pre = (lt + 1 < ntl);
    u16x8 v0n, v1n;
    if (pre) {  // issue next-tile loads BEFORE compute (2-phase pipeline)
      const int kvn = kv0 + 64;
      #pragma unroll
      for (int ii = 0; ii < 2; ++ii) {
        int rb = w * 16 + ii * 8;
        int row = rb + (l >> 3);
        int ch = (l & 7) ^ (row & 7);
        gload_lds16(qkv + (row0 + kvn + row) * 3072 + 1024 + h * 64 + ch * 8,
                    &K_lds[cur ^ 1][rb * 64]);
      }
      size_t tr = row0 + kvn + 2 * vp;
      v0n = *(const u16x8*)(qkv + tr * 3072 + 2048 + h * 64 + vcb * 8);
      v1n = *(const u16x8*)(qkv + (tr + 1) * 3072 + 2048 + h * 64 + vcb * 8);
    }
    const char* Kb = (const char*)K_lds[cur];
    const char* Vb = (const char*)V_lds[cur];
    // ---- S = Q K^T (raw scores; scale folded into exp2 FMA below)
    f32x4 s[4] = {};
    #pragma unroll
    for (int ks = 0; ks < 2; ++ks) {
      bf16x8 kf[4];
      #pragma unroll
      for (int nk = 0; nk < 4; ++nk) {
        int row = nk * 16 + c;
        kf[nk] = *(const bf16x8*)(Kb + row * 128 + ((ks * 64 + g * 16) ^ ((row & 7) << 4)));
      }
      __builtin_amdgcn_s_setprio(1);
      #pragma unroll
      for (int nk = 0; nk < 4; ++nk)
        s[nk] = __builtin_amdgcn_mfma_f32_16x16x32_bf16(qf[ks], kf[nk], s[nk], 0, 0, 0);
      __builtin_amdgcn_s_setprio(0);
    }
    // ---- causal mask only on the diagonal tile (wave-uniform branch)
    if (hasdiag && lt == ntl - 1) {
      #pragma unroll
      for (int nk = 0; nk < 4; ++nk)
        #pragma unroll
        for (int r = 0; r < 4; ++r) {
          int rowg = q0w + 4 * g + r;
          int colg = kv0 + nk * 16 + c;
          if (colg > rowg) s[nk][r] = -1e30f;
        }
    }
    // ---- online softmax: row-max reduce, alpha==1 fast path, per-lane l-partials
    float mx[4];
    #pragma unroll
    for (int r = 0; r < 4; ++r) {
      float m0 = fmaxf(fmaxf(s[0][r], s[1][r]), fmaxf(s[2][r], s[3][r]));
      m0 = fmaxf(m0, __shfl_xor(m0, 1));
      m0 = fmaxf(m0, __shfl_xor(m0, 2));
      m0 = fmaxf(m0, __shfl_xor(m0, 4));
      m0 = fmaxf(m0, __shfl_xor(m0, 8));
      mx[r] = m0;
    }
    bool nogrow = (mx[0] <= mstate[0]) & (mx[1] <= mstate[1]) &
                  (mx[2] <= mstate[2]) & (mx[3] <= mstate[3]);
    if (!__all(nogrow)) {
      #pragma unroll
      for (int r = 0; r < 4; ++r) {
        float mold = mstate[r];
        float mnew = fmaxf(mold, mx[r]);
        float alpha = exp2f((mold - mnew) * SCL);
        mstate[r] = mnew;
        lstate[r] *= alpha;
        #pragma unroll
        for (int nd = 0; nd < 4; ++nd) acc[nd][r] *= alpha;
      }
    }
    #pragma unroll
    for (int r = 0; r < 4; ++r) {
      float ms = mstate[r] * SCL;
      float p0 = exp2f(fmaf(s[0][r], SCL, -ms));
      float p1 = exp2f(fmaf(s[1][r], SCL, -ms));
      float p2 = exp2f(fmaf(s[2][r], SCL, -ms));
      float p3 = exp2f(fmaf(s[3][r], SCL, -ms));
      s[0][r] = p0; s[1][r] = p1; s[2][r] = p2; s[3][r] = p3;
      lstate[r] += (p0 + p1) + (p2 + p3);   // per-lane partial; reduced in epilogue
    }
    // ---- P -> LDS (bf16, swizzled; per-wave buffer, in-wave lgkm sync only)
    #pragma unroll
    for (int nk = 0; nk < 4; ++nk)
      #pragma unroll
      for (int r = 0; r < 4; ++r) {
        int row = 4 * g + r;
        int off = row * 128 + (((nk * 16 + c) * 2) ^ ((row & 7) << 4));
        *(unsigned short*)(Pb + off) = f2b(s[nk][r]);
      }
    // ---- O += P V
    #pragma unroll
    for (int ks = 0; ks < 2; ++ks) {
      bf16x8 pf, vf[4];
      pf = *(const bf16x8*)(Pb + c * 128 + ((ks * 64 + g * 16) ^ ((c & 7) << 4)));
      #pragma unroll
      for (int nd = 0; nd < 4; ++nd) {
        int row = nd * 16 + c;
        vf[nd] = *(const bf16x8*)(Vb + row * 128 + ((ks * 64 + g * 16) ^ ((row & 7) << 4)));
      }
      __builtin_amdgcn_s_setprio(1);
      #pragma unroll
      for (int nd = 0; nd < 4; ++nd)
        acc[nd] = __builtin_amdgcn_mfma_f32_16x16x32_bf16(pf, vf[nd], acc[nd], 0, 0, 0);
      __builtin_amdgcn_s_setprio(0);
    }
    if (pre) {  // write prefetched V into next buffer (vmcnt wait lands here)
      char* Vbn = (char*)V_lds[cur ^ 1];
      #pragma unroll
      for (int jj = 0; jj < 8; ++jj) {
        int d = vcb * 8 + jj;
        int off = d * 128 + ((4 * vp) ^ ((d & 7) << 4));
        *(unsigned int*)(Vbn + off) = (unsigned int)v0n[jj] | ((unsigned int)v1n[jj] << 16);
      }
    }
    __syncthreads();  // one barrier per tile
  }

  // ---- epilogue: reduce l across the 16-lane group, write UNNORMALIZED partial
  #pragma unroll
  for (int r = 0; r < 4; ++r) {
    float ls = lstate[r];
    ls += __shfl_xor(ls, 1);
    ls += __shfl_xor(ls, 2);
    ls += __shfl_xor(ls, 4);
    ls += __shfl_xor(ls, 8);
    int row = w * 16 + 4 * g + r;                  // 0..63 within q-tile
    #pragma unroll
    for (int nd = 0; nd < 4; ++nd)
      partO[(size_t)bid * 4096 + row * 64 + nd * 16 + c] = f2b(acc[nd][r]);
    if (c == 0) {
      partML[(size_t)bid * 128 + row * 2 + 0] = mstate[r];
      partML[(size_t)bid * 128 + row * 2 + 1] = ls;
    }
  }
}

// ---------------- combine: merge <=4 KV-chunk partials per q-tile ----------------
__global__ __launch_bounds__(256) void attn_combine(const unsigned short* __restrict__ partO,
                                                    const float* __restrict__ partML,
                                                    unsigned short* __restrict__ out) {
  const int bid = blockIdx.x;                      // 1024 = 32 qt x 32 bh
  const int qt = bid >> 5, bh = bid & 31;
  const int b = bh >> 4, h = bh & 15;
  const int np = (qt >> 3) + 1;                    // partials: ceil((qt+1)/8)
  const int t = threadIdx.x;
  const int row = t >> 2, cg = (t & 3) * 16;       // 64 rows x 4 col-groups of 16
  const float SCL = 0.18033688f;
  // chunk slots for this qt (see attn_kernel map)
  int slot0 = ((qt +  0) << 5) | bh;
  int slot1 = ((qt + 24) << 5) | bh;
  int slot2 = ((qt + 40) << 5) | bh;
  int slot3 = ((qt + 48) << 5) | bh;
  float mstar = partML[(size_t)slot0 * 128 + row * 2];
  if (np > 1) mstar = fmaxf(mstar, partML[(size_t)slot1 * 128 + row * 2]);
  if (np > 2) mstar = fmaxf(mstar, partML[(size_t)slot2 * 128 + row * 2]);
  if (np > 3) mstar = fmaxf(mstar, partML[(size_t)slot3 * 128 + row * 2]);
  float L = 0.f;
  float o[16];
  #pragma unroll
  for (int j = 0; j < 16; ++j) o[j] = 0.f;
  #pragma unroll
  for (int p = 0; p < 4; ++p) {
    if (p < np) {
      int slot = p == 0 ? slot0 : (p == 1 ? slot1 : (p == 2 ? slot2 : slot3));
      float mp = partML[(size_t)slot * 128 + row * 2 + 0];
      float lp = partML[(size_t)slot * 128 + row * 2 + 1];
      float wgt = exp2f((mp - mstar) * SCL);
      L = fmaf(wgt, lp, L);
      const unsigned short* src = partO + (size_t)slot * 4096 + row * 64 + cg;
      u16x8 a = *(const u16x8*)src;
      u16x8 bb = *(const u16x8*)(src + 8);
      #pragma unroll
      for (int j = 0; j < 8; ++j) {
        o[j]     = fmaf(b2f(a[j]),  wgt, o[j]);
        o[j + 8] = fmaf(b2f(bb[j]), wgt, o[j + 8]);
      }
    }
  }
  float rinv = 1.0f / L;
  u16x8 r0, r1;
  #pragma unroll
  for (int j = 0; j < 8; ++j) {
    r0[j] = f2b(o[j] * rinv);
    r1[j] = f2b(o[j + 8] * rinv);
  }
  size_t trow = (size_t)b * 2048 + qt * 64 + row;
  *(u16x8*)(out + trow * 1024 + h * 64 + cg) = r0;
  *(u16x8*)(out + trow * 1024 + h * 64 + cg + 8) = r1;
}

// ---------------- launch ----------------
extern "C" void kernel_launch(void* const* d_in, const int* in_sizes, int n_in,
                              void* d_out, int out_size, void* d_ws, size_t ws_size,
                              hipStream_t stream) {
  const float* x      = (const float*)d_in[0];
  const float* W_attn = (const float*)d_in[1];
  const float* b_attn = (const float*)d_in[2];
  const float* W_proj = (const float*)d_in[3];
  const float* b_proj = (const float*)d_in[4];
  float* out = (float*)d_out;

  char* ws = (char*)d_ws;
  // layout (overlap-aware; total 55.3 MB):
  //   Wproj_t  [0,        2097152)   needed until GEMM2
  //   qkv      [2097152,  27262976)  needed until combine... (attn reads it)
  //   x_bf     [27262976, 35651584)  dead after GEMM1  \ overlapped by partO
  //   Wattn_t  [35651584, 41943040)  dead after GEMM1  /
  //   partO    [27262976, 48234496)  written by attn (after GEMM1 done)
  //   attn_out [48234496, 56623104)
  //   partML   [56623104, 57933824)
  unsigned short* Wproj_t  = (unsigned short*)(ws + 0);
  unsigned short* qkv      = (unsigned short*)(ws + 2097152);
  unsigned short* x_bf     = (unsigned short*)(ws + 27262976);
  unsigned short* Wattn_t  = (unsigned short*)(ws + 35651584);
  unsigned short* partO    = (unsigned short*)(ws + 27262976);
  unsigned short* attn_out = (unsigned short*)(ws + 48234496);
  float*          partML   = (float*)(ws + 56623104);

  convert_f32_bf16<<<2048, 256, 0, stream>>>(x, x_bf, 4194304);
  transpose_f32_bf16<<<dim3(96, 32), dim3(32, 8), 0, stream>>>(W_attn, Wattn_t, 1024, 3072);
  transpose_f32_bf16<<<dim3(32, 32), dim3(32, 8), 0, stream>>>(W_proj, Wproj_t, 1024, 1024);

  gemm_bt<true><<<dim3(32, 24), 256, 0, stream>>>(x_bf, Wattn_t, b_attn, qkv, 4096, 3072, 1024);
  attn_kernel<<<2560, 256, 0, stream>>>(qkv, partO, partML);
  attn_combine<<<1024, 256, 0, stream>>>(partO, partML, attn_out);
  gemm_bt<false><<<dim3(32, 8), 256, 0, stream>>>(attn_out, Wproj_t, b_proj, out, 4096, 1024, 1024);
}

// Round 8
// 153.244 us; speedup vs baseline: 1.1532x; 1.0699x over previous
//
#include <hip/hip_runtime.h>
#include <stdint.h>

typedef __attribute__((ext_vector_type(4))) float f32x4;
typedef __attribute__((ext_vector_type(8))) __bf16 bf16x8;
typedef __attribute__((ext_vector_type(8))) unsigned short u16x8;

__device__ __forceinline__ unsigned short f2b(float f) {
  unsigned u = __float_as_uint(f);
  u += 0x7FFFu + ((u >> 16) & 1u);   // RNE
  return (unsigned short)(u >> 16);
}
__device__ __forceinline__ float b2f(unsigned short s) {
  unsigned u = (unsigned)s << 16;
  return __uint_as_float(u);
}
__device__ __forceinline__ unsigned cvtpk_bf16(float lo, float hi) {
  unsigned r;
  asm("v_cvt_pk_bf16_f32 %0, %1, %2" : "=v"(r) : "v"(lo), "v"(hi));
  return r;
}

__device__ __forceinline__ void gload_lds16(const void* g, void* l) {
  typedef __attribute__((address_space(1))) void GV1;
  typedef __attribute__((address_space(3))) void LV3;
  __builtin_amdgcn_global_load_lds((GV1*)(void*)g, (LV3*)l, 16, 0, 0);
}

// ---------------- conversion kernels ----------------
__global__ __launch_bounds__(256) void convert_f32_bf16(const float* __restrict__ in,
                                                        unsigned short* __restrict__ out, int n) {
  int i = (blockIdx.x * 256 + threadIdx.x) * 8;
  if (i >= n) return;
  float4 a = *(const float4*)(in + i);
  float4 b = *(const float4*)(in + i + 4);
  u16x8 r;
  r[0] = f2b(a.x); r[1] = f2b(a.y); r[2] = f2b(a.z); r[3] = f2b(a.w);
  r[4] = f2b(b.x); r[5] = f2b(b.y); r[6] = f2b(b.z); r[7] = f2b(b.w);
  *(u16x8*)(out + i) = r;
}

// W [K][N] f32 -> Wt [N][K] bf16
__global__ __launch_bounds__(256) void transpose_f32_bf16(const float* __restrict__ W,
                                                          unsigned short* __restrict__ Wt,
                                                          int K, int N) {
  __shared__ unsigned short tile[32][33];
  int n0 = blockIdx.x * 32, k0 = blockIdx.y * 32;
  int tx = threadIdx.x, ty = threadIdx.y;  // 32 x 8
  #pragma unroll
  for (int j = 0; j < 32; j += 8)
    tile[ty + j][tx] = f2b(W[(size_t)(k0 + ty + j) * N + n0 + tx]);
  __syncthreads();
  #pragma unroll
  for (int j = 0; j < 32; j += 8)
    Wt[(size_t)(n0 + ty + j) * K + k0 + tx] = tile[tx][ty + j];
}

// ---------------- GEMM: C[M][N] = A[M][K] * Bt[N][K]^T + bias ----------------
template <bool OUT_BF16>
__global__ __launch_bounds__(256) void gemm_bt(const unsigned short* __restrict__ A,
                                               const unsigned short* __restrict__ Bt,
                                               const float* __restrict__ bias,
                                               void* __restrict__ Cout,
                                               int M, int N, int K) {
  __shared__ unsigned short As[128 * 64];
  __shared__ unsigned short Bs[128 * 64];
  const int m0 = blockIdx.x * 128, n0 = blockIdx.y * 128;
  const int tid = threadIdx.x;
  const int w = tid >> 6, l = tid & 63;
  const int wm = w >> 1, wn = w & 1;
  const int c = l & 15, g = l >> 4;
  f32x4 acc[4][4] = {};
  for (int k0 = 0; k0 < K; k0 += 64) {
    #pragma unroll
    for (int i = 0; i < 4; ++i) {
      int rb = w * 32 + i * 8;
      gload_lds16(A + (size_t)(m0 + rb + (l >> 3)) * K + k0 + (l & 7) * 8, &As[rb * 64]);
      gload_lds16(Bt + (size_t)(n0 + rb + (l >> 3)) * K + k0 + (l & 7) * 8, &Bs[rb * 64]);
    }
    __syncthreads();
    #pragma unroll
    for (int ks = 0; ks < 2; ++ks) {
      bf16x8 af[4], bf[4];
      #pragma unroll
      for (int mi = 0; mi < 4; ++mi)
        af[mi] = *(const bf16x8*)&As[(wm * 64 + mi * 16 + c) * 64 + ks * 32 + g * 8];
      #pragma unroll
      for (int ni = 0; ni < 4; ++ni)
        bf[ni] = *(const bf16x8*)&Bs[(wn * 64 + ni * 16 + c) * 64 + ks * 32 + g * 8];
      #pragma unroll
      for (int mi = 0; mi < 4; ++mi)
        #pragma unroll
        for (int ni = 0; ni < 4; ++ni)
          acc[mi][ni] = __builtin_amdgcn_mfma_f32_16x16x32_bf16(af[mi], bf[ni], acc[mi][ni], 0, 0, 0);
    }
    __syncthreads();
  }
  #pragma unroll
  for (int mi = 0; mi < 4; ++mi) {
    #pragma unroll
    for (int ni = 0; ni < 4; ++ni) {
      int colg = n0 + wn * 64 + ni * 16 + c;
      float bv = bias[colg];
      #pragma unroll
      for (int r = 0; r < 4; ++r) {
        int rowg = m0 + wm * 64 + mi * 16 + 4 * g + r;
        float v = acc[mi][ni][r] + bv;
        if (OUT_BF16)
          ((unsigned short*)Cout)[(size_t)rowg * N + colg] = f2b(v);
        else
          ((float*)Cout)[(size_t)rowg * N + colg] = v;
      }
    }
  }
}

// ---------------- causal flash attention, SPLIT-KV + SWAPPED MFMA ----------------
// qkv [4096][3072] bf16. Block = one 64-row q-tile x one KV chunk of <=8 tiles.
// SWAPPED OPERANDS (R7): S^T = mfma(K,Q) -> lane holds S[q=c][kv=16nk+4g+r]
// (16 kv for ONE q-row): row-max = in-lane tree + 2 shfls (was 16); m/l/alpha
// lane-local. O^T = mfma(V^T, P^T-frag) -> acc q=c, normalize lane-local.
// P^T B-frag built in-register: 8 cvt_pk + 16 ds_bpermute; P_lds DELETED
// (LDS 32KB -> up to 5 blocks/CU). A/B frags have identical per-lane layout
// so ALL loads (Q,K,V staging incl. swizzles) are unchanged from R6.
__global__ __launch_bounds__(256) void attn_kernel(const unsigned short* __restrict__ qkv,
                                                   unsigned short* __restrict__ partO,
                                                   float* __restrict__ partML) {
  __shared__ unsigned short K_lds[2][64 * 64];     // [kv][d], XOR-swizzled rows
  __shared__ unsigned short V_lds[2][64 * 64];     // V^T [d][kv], XOR-swizzled rows
  const int bid = blockIdx.x;
  const int bh = bid & 31;
  const int cid = bid >> 5;
  int qt, ct;
  if (cid < 32)      { qt = cid;      ct = 0; }
  else if (cid < 56) { qt = cid - 24; ct = 1; }
  else if (cid < 72) { qt = cid - 40; ct = 2; }
  else               { qt = cid - 48; ct = 3; }
  const int t0 = ct * 8;
  const int ntl = min(qt + 1 - t0, 8);
  const bool hasdiag = (t0 + ntl - 1) == qt;
  const int b = bh >> 4, h = bh & 15;
  const int tid = threadIdx.x, w = tid >> 6, l = tid & 63;
  const int c = l & 15, g = l >> 4;
  const int hi = g >> 1;
  const int srcA = c + ((g & 1) << 5);             // bpermute pattern A (j=0,1)
  const int srcB = srcA + 16;                      // pattern B (j=2,3)
  const size_t row0 = (size_t)b * 2048;
  const int vp = tid & 31, vcb = tid >> 5;
  const float SCL = 0.18033688f;                   // 0.125 * log2(e)

  const int q0w = qt * 64 + w * 16;
  const int qg = q0w + c;                          // this lane's q row (global)

  // Q fragments (unchanged bytes; now consumed as the B operand)
  bf16x8 qf[2];
  #pragma unroll
  for (int ks = 0; ks < 2; ++ks)
    qf[ks] = *(const bf16x8*)(qkv + (row0 + qg) * 3072 + h * 64 + ks * 32 + g * 8);

  f32x4 acc[4] = {};                               // O^T: acc[nd][r] = O[q=c][d=16nd+4g+r]
  float mstate = -1e30f, lstate = 0.f;             // lane-local (q=c); l is per-lane partial

  // ---- prologue: stage kv-tile t0 into buffer 0
  {
    #pragma unroll
    for (int i = 0; i < 2; ++i) {
      int rb = w * 16 + i * 8;
      int row = rb + (l >> 3);
      int ch = (l & 7) ^ (row & 7);                // pre-swizzled source (m173)
      gload_lds16(qkv + (row0 + t0 * 64 + row) * 3072 + 1024 + h * 64 + ch * 8,
                  &K_lds[0][rb * 64]);
    }
    size_t tr = row0 + t0 * 64 + 2 * vp;
    u16x8 v0 = *(const u16x8*)(qkv + tr * 3072 + 2048 + h * 64 + vcb * 8);
    u16x8 v1 = *(const u16x8*)(qkv + (tr + 1) * 3072 + 2048 + h * 64 + vcb * 8);
    char* Vb = (char*)V_lds[0];
    #pragma unroll
    for (int jj = 0; jj < 8; ++jj) {
      int d = vcb * 8 + jj;
      int off = d * 128 + ((4 * vp) ^ ((d & 7) << 4));
      *(unsigned int*)(Vb + off) = (unsigned int)v0[jj] | ((unsigned int)v1[jj] << 16);
    }
  }
  __syncthreads();

  for (int lt = 0; lt < ntl; ++lt) {
    const int cur = lt & 1;
    const int kv0 = (t0 + lt) * 64;
    const bool pre = (lt + 1 < ntl);
    u16x8 v0n, v1n;
    if (pre) {  // issue next-tile loads BEFORE compute (2-phase pipeline)
      const int kvn = kv0 + 64;
      #pragma unroll
      for (int ii = 0; ii < 2; ++ii) {
        int rb = w * 16 + ii * 8;
        int row = rb + (l >> 3);
        int ch = (l & 7) ^ (row & 7);
        gload_lds16(qkv + (row0 + kvn + row) * 3072 + 1024 + h * 64 + ch * 8,
                    &K_lds[cur ^ 1][rb * 64]);
      }
      size_t tr = row0 + kvn + 2 * vp;
      v0n = *(const u16x8*)(qkv + tr * 3072 + 2048 + h * 64 + vcb * 8);
      v1n = *(const u16x8*)(qkv + (tr + 1) * 3072 + 2048 + h * 64 + vcb * 8);
    }
    const char* Kb = (const char*)K_lds[cur];
    const char* Vb = (const char*)V_lds[cur];
    // ---- S^T = mfma(K, Q): s[nk][r] = S[q=qg][kv = kv0 + 16nk + 4g + r]
    f32x4 s[4] = {};
    #pragma unroll
    for (int ks = 0; ks < 2; ++ks) {
      bf16x8 kf[4];
      #pragma unroll
      for (int nk = 0; nk < 4; ++nk) {
        int row = nk * 16 + c;
        kf[nk] = *(const bf16x8*)(Kb + row * 128 + ((ks * 64 + g * 16) ^ ((row & 7) << 4)));
      }
      __builtin_amdgcn_s_setprio(1);
      #pragma unroll
      for (int nk = 0; nk < 4; ++nk)
        s[nk] = __builtin_amdgcn_mfma_f32_16x16x32_bf16(kf[nk], qf[ks], s[nk], 0, 0, 0);
      __builtin_amdgcn_s_setprio(0);
    }
    // ---- causal mask only on the diagonal tile
    if (hasdiag && lt == ntl - 1) {
      #pragma unroll
      for (int nk = 0; nk < 4; ++nk)
        #pragma unroll
        for (int r = 0; r < 4; ++r) {
          int kvg = kv0 + nk * 16 + 4 * g + r;
          if (kvg > qg) s[nk][r] = -1e30f;
        }
    }
    // ---- row max: in-lane tree + 2 shfls (lanes c,c+16,c+32,c+48 share q)
    float a0 = fmaxf(fmaxf(s[0][0], s[0][1]), fmaxf(s[0][2], s[0][3]));
    float a1 = fmaxf(fmaxf(s[1][0], s[1][1]), fmaxf(s[1][2], s[1][3]));
    float a2 = fmaxf(fmaxf(s[2][0], s[2][1]), fmaxf(s[2][2], s[2][3]));
    float a3 = fmaxf(fmaxf(s[3][0], s[3][1]), fmaxf(s[3][2], s[3][3]));
    float mx = fmaxf(fmaxf(a0, a1), fmaxf(a2, a3));
    mx = fmaxf(mx, __shfl_xor(mx, 16));
    mx = fmaxf(mx, __shfl_xor(mx, 32));
    // ---- alpha==1 fast path (wave-uniform); rescale fully lane-local
    if (!__all(mx <= mstate)) {
      float mnew = fmaxf(mstate, mx);
      float alpha = exp2f((mstate - mnew) * SCL);
      mstate = mnew;
      lstate *= alpha;
      #pragma unroll
      for (int nd = 0; nd < 4; ++nd) acc[nd] *= alpha;
    }
    // ---- P = exp2(s*SCL - m*SCL), per-lane l partial
    float ms = mstate * SCL;
    #pragma unroll
    for (int nk = 0; nk < 4; ++nk) {
      #pragma unroll
      for (int r = 0; r < 4; ++r) s[nk][r] = exp2f(fmaf(s[nk][r], SCL, -ms));
      lstate += (s[nk][0] + s[nk][1]) + (s[nk][2] + s[nk][3]);
    }
    // ---- pack P to bf16 pairs: pk[nk][jj] = (kv 16nk+4g+2jj, +1) for q=c
    unsigned pk[4][2];
    #pragma unroll
    for (int nk = 0; nk < 4; ++nk) {
      pk[nk][0] = cvtpk_bf16(s[nk][0], s[nk][1]);
      pk[nk][1] = cvtpk_bf16(s[nk][2], s[nk][3]);
    }
    // ---- O^T += mfma(V^T, P^T): B-frag pa[vks] = P[q=c][kv=32vks+8g+e]
    #pragma unroll
    for (int vks = 0; vks < 2; ++vks) {
      unsigned rA00 = __shfl(pk[2 * vks][0], srcA, 64);
      unsigned rA01 = __shfl(pk[2 * vks][1], srcA, 64);
      unsigned rA10 = __shfl(pk[2 * vks + 1][0], srcA, 64);
      unsigned rA11 = __shfl(pk[2 * vks + 1][1], srcA, 64);
      unsigned rB00 = __shfl(pk[2 * vks][0], srcB, 64);
      unsigned rB01 = __shfl(pk[2 * vks][1], srcB, 64);
      unsigned rB10 = __shfl(pk[2 * vks + 1][0], srcB, 64);
      unsigned rB11 = __shfl(pk[2 * vks + 1][1], srcB, 64);
      union { unsigned u[4]; bf16x8 v; } pa;
      pa.u[0] = hi ? rA10 : rA00;
      pa.u[1] = hi ? rA11 : rA01;
      pa.u[2] = hi ? rB10 : rB00;
      pa.u[3] = hi ? rB11 : rB01;
      bf16x8 vf[4];
      #pragma unroll
      for (int nd = 0; nd < 4; ++nd) {
        int row = nd * 16 + c;
        vf[nd] = *(const bf16x8*)(Vb + row * 128 + ((vks * 64 + g * 16) ^ ((row & 7) << 4)));
      }
      __builtin_amdgcn_s_setprio(1);
      #pragma unroll
      for (int nd = 0; nd < 4; ++nd)
        acc[nd] = __builtin_amdgcn_mfma_f32_16x16x32_bf16(vf[nd], pa.v, acc[nd], 0, 0, 0);
      __builtin_amdgcn_s_setprio(0);
    }
    if (pre) {  // write prefetched V into next buffer (vmcnt wait lands here)
      char* Vbn = (char*)V_lds[cur ^ 1];
      #pragma unroll
      for (int jj = 0; jj < 8; ++jj) {
        int d = vcb * 8 + jj;
        int off = d * 128 + ((4 * vp) ^ ((d & 7) << 4));
        *(unsigned int*)(Vbn + off) = (unsigned int)v0n[jj] | ((unsigned int)v1n[jj] << 16);
      }
    }
    __syncthreads();  // one barrier per tile
  }

  // ---- epilogue: reduce l over the 4 g-lanes sharing q=c; write partials
  float lsum = lstate;
  lsum += __shfl_xor(lsum, 16);
  lsum += __shfl_xor(lsum, 32);
  const int qrow = w * 16 + c;                     // 0..63 within q-tile
  #pragma unroll
  for (int nd = 0; nd < 4; ++nd) {
    ushort4 o4;
    o4.x = f2b(acc[nd][0]); o4.y = f2b(acc[nd][1]);
    o4.z = f2b(acc[nd][2]); o4.w = f2b(acc[nd][3]);
    *(ushort4*)(partO + (size_t)bid * 4096 + qrow * 64 + nd * 16 + 4 * g) = o4;
  }
  if (g == 0) {
    partML[(size_t)bid * 128 + qrow * 2 + 0] = mstate;
    partML[(size_t)bid * 128 + qrow * 2 + 1] = lsum;
  }
}

// ---------------- combine: merge <=4 KV-chunk partials per q-tile ----------------
__global__ __launch_bounds__(256) void attn_combine(const unsigned short* __restrict__ partO,
                                                    const float* __restrict__ partML,
                                                    unsigned short* __restrict__ out) {
  const int bid = blockIdx.x;                      // 1024 = 32 qt x 32 bh
  const int qt = bid >> 5, bh = bid & 31;
  const int b = bh >> 4, h = bh & 15;
  const int np = (qt >> 3) + 1;                    // partials: ceil((qt+1)/8)
  const int t = threadIdx.x;
  const int row = t >> 2, cg = (t & 3) * 16;       // 64 rows x 4 col-groups of 16
  const float SCL = 0.18033688f;
  int slot0 = ((qt +  0) << 5) | bh;
  int slot1 = ((qt + 24) << 5) | bh;
  int slot2 = ((qt + 40) << 5) | bh;
  int slot3 = ((qt + 48) << 5) | bh;
  float mstar = partML[(size_t)slot0 * 128 + row * 2];
  if (np > 1) mstar = fmaxf(mstar, partML[(size_t)slot1 * 128 + row * 2]);
  if (np > 2) mstar = fmaxf(mstar, partML[(size_t)slot2 * 128 + row * 2]);
  if (np > 3) mstar = fmaxf(mstar, partML[(size_t)slot3 * 128 + row * 2]);
  float L = 0.f;
  float o[16];
  #pragma unroll
  for (int j = 0; j < 16; ++j) o[j] = 0.f;
  #pragma unroll
  for (int p = 0; p < 4; ++p) {
    if (p < np) {
      int slot = p == 0 ? slot0 : (p == 1 ? slot1 : (p == 2 ? slot2 : slot3));
      float mp = partML[(size_t)slot * 128 + row * 2 + 0];
      float lp = partML[(size_t)slot * 128 + row * 2 + 1];
      float wgt = exp2f((mp - mstar) * SCL);
      L = fmaf(wgt, lp, L);
      const unsigned short* src = partO + (size_t)slot * 4096 + row * 64 + cg;
      u16x8 a = *(const u16x8*)src;
      u16x8 bb = *(const u16x8*)(src + 8);
      #pragma unroll
      for (int j = 0; j < 8; ++j) {
        o[j]     = fmaf(b2f(a[j]),  wgt, o[j]);
        o[j + 8] = fmaf(b2f(bb[j]), wgt, o[j + 8]);
      }
    }
  }
  float rinv = 1.0f / L;
  u16x8 r0, r1;
  #pragma unroll
  for (int j = 0; j < 8; ++j) {
    r0[j] = f2b(o[j] * rinv);
    r1[j] = f2b(o[j + 8] * rinv);
  }
  size_t trow = (size_t)b * 2048 + qt * 64 + row;
  *(u16x8*)(out + trow * 1024 + h * 64 + cg) = r0;
  *(u16x8*)(out + trow * 1024 + h * 64 + cg + 8) = r1;
}

// ---------------- launch ----------------
extern "C" void kernel_launch(void* const* d_in, const int* in_sizes, int n_in,
                              void* d_out, int out_size, void* d_ws, size_t ws_size,
                              hipStream_t stream) {
  const float* x      = (const float*)d_in[0];
  const float* W_attn = (const float*)d_in[1];
  const float* b_attn = (const float*)d_in[2];
  const float* W_proj = (const float*)d_in[3];
  const float* b_proj = (const float*)d_in[4];
  float* out = (float*)d_out;

  char* ws = (char*)d_ws;
  unsigned short* Wproj_t  = (unsigned short*)(ws + 0);
  unsigned short* qkv      = (unsigned short*)(ws + 2097152);
  unsigned short* x_bf     = (unsigned short*)(ws + 27262976);
  unsigned short* Wattn_t  = (unsigned short*)(ws + 35651584);
  unsigned short* partO    = (unsigned short*)(ws + 27262976);   // overlaps x_bf/Wattn_t (dead)
  unsigned short* attn_out = (unsigned short*)(ws + 48234496);
  float*          partML   = (float*)(ws + 56623104);

  convert_f32_bf16<<<2048, 256, 0, stream>>>(x, x_bf, 4194304);
  transpose_f32_bf16<<<dim3(96, 32), dim3(32, 8), 0, stream>>>(W_attn, Wattn_t, 1024, 3072);
  transpose_f32_bf16<<<dim3(32, 32), dim3(32, 8), 0, stream>>>(W_proj, Wproj_t, 1024, 1024);

  gemm_bt<true><<<dim3(32, 24), 256, 0, stream>>>(x_bf, Wattn_t, b_attn, qkv, 4096, 3072, 1024);
  attn_kernel<<<2560, 256, 0, stream>>>(qkv, partO, partML);
  attn_combine<<<1024, 256, 0, stream>>>(partO, partML, attn_out);
  gemm_bt<false><<<dim3(32, 8), 256, 0, stream>>>(attn_out, Wproj_t, b_proj, out, 4096, 1024, 1024);
}

// Round 9
// 153.053 us; speedup vs baseline: 1.1546x; 1.0012x over previous
//
#include <hip/hip_runtime.h>
#include <stdint.h>

typedef __attribute__((ext_vector_type(4))) float f32x4;
typedef __attribute__((ext_vector_type(8))) __bf16 bf16x8;
typedef __attribute__((ext_vector_type(8))) unsigned short u16x8;

__device__ __forceinline__ unsigned short f2b(float f) {
  unsigned u = __float_as_uint(f);
  u += 0x7FFFu + ((u >> 16) & 1u);   // RNE
  return (unsigned short)(u >> 16);
}
__device__ __forceinline__ float b2f(unsigned short s) {
  unsigned u = (unsigned)s << 16;
  return __uint_as_float(u);
}
__device__ __forceinline__ unsigned cvtpk_bf16(float lo, float hi) {
  unsigned r;
  asm("v_cvt_pk_bf16_f32 %0, %1, %2" : "=v"(r) : "v"(lo), "v"(hi));
  return r;
}

__device__ __forceinline__ void gload_lds16(const void* g, void* l) {
  typedef __attribute__((address_space(1))) void GV1;
  typedef __attribute__((address_space(3))) void LV3;
  __builtin_amdgcn_global_load_lds((GV1*)(void*)g, (LV3*)l, 16, 0, 0);
}

// ---------------- conversion kernels ----------------
__global__ __launch_bounds__(256) void convert_f32_bf16(const float* __restrict__ in,
                                                        unsigned short* __restrict__ out, int n) {
  int i = (blockIdx.x * 256 + threadIdx.x) * 8;
  if (i >= n) return;
  float4 a = *(const float4*)(in + i);
  float4 b = *(const float4*)(in + i + 4);
  u16x8 r;
  r[0] = f2b(a.x); r[1] = f2b(a.y); r[2] = f2b(a.z); r[3] = f2b(a.w);
  r[4] = f2b(b.x); r[5] = f2b(b.y); r[6] = f2b(b.z); r[7] = f2b(b.w);
  *(u16x8*)(out + i) = r;
}

// W [K][N] f32 -> Wt [N][K] bf16
__global__ __launch_bounds__(256) void transpose_f32_bf16(const float* __restrict__ W,
                                                          unsigned short* __restrict__ Wt,
                                                          int K, int N) {
  __shared__ unsigned short tile[32][33];
  int n0 = blockIdx.x * 32, k0 = blockIdx.y * 32;
  int tx = threadIdx.x, ty = threadIdx.y;  // 32 x 8
  #pragma unroll
  for (int j = 0; j < 32; j += 8)
    tile[ty + j][tx] = f2b(W[(size_t)(k0 + ty + j) * N + n0 + tx]);
  __syncthreads();
  #pragma unroll
  for (int j = 0; j < 32; j += 8)
    Wt[(size_t)(n0 + ty + j) * K + k0 + tx] = tile[tx][ty + j];
}

// ---------------- GEMM: C[M][N] = A[M][K] * Bt[N][K]^T + bias ----------------
template <bool OUT_BF16>
__global__ __launch_bounds__(256) void gemm_bt(const unsigned short* __restrict__ A,
                                               const unsigned short* __restrict__ Bt,
                                               const float* __restrict__ bias,
                                               void* __restrict__ Cout,
                                               int M, int N, int K) {
  __shared__ unsigned short As[128 * 64];
  __shared__ unsigned short Bs[128 * 64];
  const int m0 = blockIdx.x * 128, n0 = blockIdx.y * 128;
  const int tid = threadIdx.x;
  const int w = tid >> 6, l = tid & 63;
  const int wm = w >> 1, wn = w & 1;
  const int c = l & 15, g = l >> 4;
  f32x4 acc[4][4] = {};
  for (int k0 = 0; k0 < K; k0 += 64) {
    #pragma unroll
    for (int i = 0; i < 4; ++i) {
      int rb = w * 32 + i * 8;
      gload_lds16(A + (size_t)(m0 + rb + (l >> 3)) * K + k0 + (l & 7) * 8, &As[rb * 64]);
      gload_lds16(Bt + (size_t)(n0 + rb + (l >> 3)) * K + k0 + (l & 7) * 8, &Bs[rb * 64]);
    }
    __syncthreads();
    #pragma unroll
    for (int ks = 0; ks < 2; ++ks) {
      bf16x8 af[4], bf[4];
      #pragma unroll
      for (int mi = 0; mi < 4; ++mi)
        af[mi] = *(const bf16x8*)&As[(wm * 64 + mi * 16 + c) * 64 + ks * 32 + g * 8];
      #pragma unroll
      for (int ni = 0; ni < 4; ++ni)
        bf[ni] = *(const bf16x8*)&Bs[(wn * 64 + ni * 16 + c) * 64 + ks * 32 + g * 8];
      #pragma unroll
      for (int mi = 0; mi < 4; ++mi)
        #pragma unroll
        for (int ni = 0; ni < 4; ++ni)
          acc[mi][ni] = __builtin_amdgcn_mfma_f32_16x16x32_bf16(af[mi], bf[ni], acc[mi][ni], 0, 0, 0);
    }
    __syncthreads();
  }
  #pragma unroll
  for (int mi = 0; mi < 4; ++mi) {
    #pragma unroll
    for (int ni = 0; ni < 4; ++ni) {
      int colg = n0 + wn * 64 + ni * 16 + c;
      float bv = bias[colg];
      #pragma unroll
      for (int r = 0; r < 4; ++r) {
        int rowg = m0 + wm * 64 + mi * 16 + 4 * g + r;
        float v = acc[mi][ni][r] + bv;
        if (OUT_BF16)
          ((unsigned short*)Cout)[(size_t)rowg * N + colg] = f2b(v);
        else
          ((float*)Cout)[(size_t)rowg * N + colg] = v;
      }
    }
  }
}

// ---------------- causal flash attention, SPLIT-KV + SWAPPED MFMA ----------------
// qkv [4096][3072] bf16. Block = one 64-row q-tile x one KV chunk of <=8 tiles.
// SWAPPED OPERANDS (R7): S^T = mfma(K,Q) -> lane holds S[q=c][kv=16nk+4g+r]
// (16 kv for ONE q-row): row-max = in-lane tree + 2 shfls (was 16); m/l/alpha
// lane-local. O^T = mfma(V^T, P^T-frag) -> acc q=c, normalize lane-local.
// P^T B-frag built in-register: 8 cvt_pk + 16 ds_bpermute; P_lds DELETED
// (LDS 32KB -> up to 5 blocks/CU). A/B frags have identical per-lane layout
// so ALL loads (Q,K,V staging incl. swizzles) are unchanged from R6.
__global__ __launch_bounds__(256) void attn_kernel(const unsigned short* __restrict__ qkv,
                                                   unsigned short* __restrict__ partO,
                                                   float* __restrict__ partML) {
  __shared__ unsigned short K_lds[2][64 * 64];     // [kv][d], XOR-swizzled rows
  __shared__ unsigned short V_lds[2][64 * 64];     // V^T [d][kv], XOR-swizzled rows
  const int bid = blockIdx.x;
  const int bh = bid & 31;
  const int cid = bid >> 5;
  int qt, ct;
  if (cid < 32)      { qt = cid;      ct = 0; }
  else if (cid < 56) { qt = cid - 24; ct = 1; }
  else if (cid < 72) { qt = cid - 40; ct = 2; }
  else               { qt = cid - 48; ct = 3; }
  const int t0 = ct * 8;
  const int ntl = min(qt + 1 - t0, 8);
  const bool hasdiag = (t0 + ntl - 1) == qt;
  const int b = bh >> 4, h = bh & 15;
  const int tid = threadIdx.x, w = tid >> 6, l = tid & 63;
  const int c = l & 15, g = l >> 4;
  const int hi = g >> 1;
  const int srcA = c + ((g & 1) << 5);             // bpermute pattern A (j=0,1)
  const int srcB = srcA + 16;                      // pattern B (j=2,3)
  const size_t row0 = (size_t)b * 2048;
  const int vp = tid & 31, vcb = tid >> 5;
  const float SCL = 0.18033688f;                   // 0.125 * log2(e)

  const int q0w = qt * 64 + w * 16;
  const int qg = q0w + c;                          // this lane's q row (global)

  // Q fragments (unchanged bytes; now consumed as the B operand)
  bf16x8 qf[2];
  #pragma unroll
  for (int ks = 0; ks < 2; ++ks)
    qf[ks] = *(const bf16x8*)(qkv + (row0 + qg) * 3072 + h * 64 + ks * 32 + g * 8);

  f32x4 acc[4] = {};                               // O^T: acc[nd][r] = O[q=c][d=16nd+4g+r]
  float mstate = -1e30f, lstate = 0.f;             // lane-local (q=c); l is per-lane partial

  // ---- prologue: stage kv-tile t0 into buffer 0
  {
    #pragma unroll
    for (int i = 0; i < 2; ++i) {
      int rb = w * 16 + i * 8;
      int row = rb + (l >> 3);
      int ch = (l & 7) ^ (row & 7);                // pre-swizzled source (m173)
      gload_lds16(qkv + (row0 + t0 * 64 + row) * 3072 + 1024 + h * 64 + ch * 8,
                  &K_lds[0][rb * 64]);
    }
    size_t tr = row0 + t0 * 64 + 2 * vp;
    u16x8 v0 = *(const u16x8*)(qkv + tr * 3072 + 2048 + h * 64 + vcb * 8);
    u16x8 v1 = *(const u16x8*)(qkv + (tr + 1) * 3072 + 2048 + h * 64 + vcb * 8);
    char* Vb = (char*)V_lds[0];
    #pragma unroll
    for (int jj = 0; jj < 8; ++jj) {
      int d = vcb * 8 + jj;
      int off = d * 128 + ((4 * vp) ^ ((d & 7) << 4));
      *(unsigned int*)(Vb + off) = (unsigned int)v0[jj] | ((unsigned int)v1[jj] << 16);
    }
  }
  __syncthreads();

  for (int lt = 0; lt < ntl; ++lt) {
    const int cur = lt & 1;
    const int kv0 = (t0 + lt) * 64;
    const bool pre = (lt + 1 < ntl);
    u16x8 v0n, v1n;
    if (pre) {  // issue next-tile loads BEFORE compute (2-phase pipeline)
      const int kvn = kv0 + 64;
      #pragma unroll
      for (int ii = 0; ii < 2; ++ii) {
        int rb = w * 16 + ii * 8;
        int row = rb + (l >> 3);
        int ch = (l & 7) ^ (row & 7);
        gload_lds16(qkv + (row0 + kvn + row) * 3072 + 1024 + h * 64 + ch * 8,
                    &K_lds[cur ^ 1][rb * 64]);
      }
      size_t tr = row0 + kvn + 2 * vp;
      v0n = *(const u16x8*)(qkv + tr * 3072 + 2048 + h * 64 + vcb * 8);
      v1n = *(const u16x8*)(qkv + (tr + 1) * 3072 + 2048 + h * 64 + vcb * 8);
    }
    const char* Kb = (const char*)K_lds[cur];
    const char* Vb = (const char*)V_lds[cur];
    // ---- S^T = mfma(K, Q): s[nk][r] = S[q=qg][kv = kv0 + 16nk + 4g + r]
    f32x4 s[4] = {};
    #pragma unroll
    for (int ks = 0; ks < 2; ++ks) {
      bf16x8 kf[4];
      #pragma unroll
      for (int nk = 0; nk < 4; ++nk) {
        int row = nk * 16 + c;
        kf[nk] = *(const bf16x8*)(Kb + row * 128 + ((ks * 64 + g * 16) ^ ((row & 7) << 4)));
      }
      __builtin_amdgcn_s_setprio(1);
      #pragma unroll
      for (int nk = 0; nk < 4; ++nk)
        s[nk] = __builtin_amdgcn_mfma_f32_16x16x32_bf16(kf[nk], qf[ks], s[nk], 0, 0, 0);
      __builtin_amdgcn_s_setprio(0);
    }
    // ---- causal mask only on the diagonal tile
    if (hasdiag && lt == ntl - 1) {
      #pragma unroll
      for (int nk = 0; nk < 4; ++nk)
        #pragma unroll
        for (int r = 0; r < 4; ++r) {
          int kvg = kv0 + nk * 16 + 4 * g + r;
          if (kvg > qg) s[nk][r] = -1e30f;
        }
    }
    // ---- row max: in-lane tree + 2 shfls (lanes c,c+16,c+32,c+48 share q)
    float a0 = fmaxf(fmaxf(s[0][0], s[0][1]), fmaxf(s[0][2], s[0][3]));
    float a1 = fmaxf(fmaxf(s[1][0], s[1][1]), fmaxf(s[1][2], s[1][3]));
    float a2 = fmaxf(fmaxf(s[2][0], s[2][1]), fmaxf(s[2][2], s[2][3]));
    float a3 = fmaxf(fmaxf(s[3][0], s[3][1]), fmaxf(s[3][2], s[3][3]));
    float mx = fmaxf(fmaxf(a0, a1), fmaxf(a2, a3));
    mx = fmaxf(mx, __shfl_xor(mx, 16));
    mx = fmaxf(mx, __shfl_xor(mx, 32));
    // ---- alpha==1 fast path (wave-uniform); rescale fully lane-local
    if (!__all(mx <= mstate)) {
      float mnew = fmaxf(mstate, mx);
      float alpha = exp2f((mstate - mnew) * SCL);
      mstate = mnew;
      lstate *= alpha;
      #pragma unroll
      for (int nd = 0; nd < 4; ++nd) acc[nd] *= alpha;
    }
    // ---- P = exp2(s*SCL - m*SCL), per-lane l partial
    float ms = mstate * SCL;
    #pragma unroll
    for (int nk = 0; nk < 4; ++nk) {
      #pragma unroll
      for (int r = 0; r < 4; ++r) s[nk][r] = exp2f(fmaf(s[nk][r], SCL, -ms));
      lstate += (s[nk][0] + s[nk][1]) + (s[nk][2] + s[nk][3]);
    }
    // ---- pack P to bf16 pairs: pk[nk][jj] = (kv 16nk+4g+2jj, +1) for q=c
    unsigned pk[4][2];
    #pragma unroll
    for (int nk = 0; nk < 4; ++nk) {
      pk[nk][0] = cvtpk_bf16(s[nk][0], s[nk][1]);
      pk[nk][1] = cvtpk_bf16(s[nk][2], s[nk][3]);
    }
    // ---- O^T += mfma(V^T, P^T): B-frag pa[vks] = P[q=c][kv=32vks+8g+e]
    #pragma unroll
    for (int vks = 0; vks < 2; ++vks) {
      unsigned rA00 = __shfl(pk[2 * vks][0], srcA, 64);
      unsigned rA01 = __shfl(pk[2 * vks][1], srcA, 64);
      unsigned rA10 = __shfl(pk[2 * vks + 1][0], srcA, 64);
      unsigned rA11 = __shfl(pk[2 * vks + 1][1], srcA, 64);
      unsigned rB00 = __shfl(pk[2 * vks][0], srcB, 64);
      unsigned rB01 = __shfl(pk[2 * vks][1], srcB, 64);
      unsigned rB10 = __shfl(pk[2 * vks + 1][0], srcB, 64);
      unsigned rB11 = __shfl(pk[2 * vks + 1][1], srcB, 64);
      union { unsigned u[4]; bf16x8 v; } pa;
      pa.u[0] = hi ? rA10 : rA00;
      pa.u[1] = hi ? rA11 : rA01;
      pa.u[2] = hi ? rB10 : rB00;
      pa.u[3] = hi ? rB11 : rB01;
      bf16x8 vf[4];
      #pragma unroll
      for (int nd = 0; nd < 4; ++nd) {
        int row = nd * 16 + c;
        vf[nd] = *(const bf16x8*)(Vb + row * 128 + ((vks * 64 + g * 16) ^ ((row & 7) << 4)));
      }
      __builtin_amdgcn_s_setprio(1);
      #pragma unroll
      for (int nd = 0; nd < 4; ++nd)
        acc[nd] = __builtin_amdgcn_mfma_f32_16x16x32_bf16(vf[nd], pa.v, acc[nd], 0, 0, 0);
      __builtin_amdgcn_s_setprio(0);
    }
    if (pre) {  // write prefetched V into next buffer (vmcnt wait lands here)
      char* Vbn = (char*)V_lds[cur ^ 1];
      #pragma unroll
      for (int jj = 0; jj < 8; ++jj) {
        int d = vcb * 8 + jj;
        int off = d * 128 + ((4 * vp) ^ ((d & 7) << 4));
        *(unsigned int*)(Vbn + off) = (unsigned int)v0n[jj] | ((unsigned int)v1n[jj] << 16);
      }
    }
    __syncthreads();  // one barrier per tile
  }

  // ---- epilogue: reduce l over the 4 g-lanes sharing q=c; write partials
  float lsum = lstate;
  lsum += __shfl_xor(lsum, 16);
  lsum += __shfl_xor(lsum, 32);
  const int qrow = w * 16 + c;                     // 0..63 within q-tile
  #pragma unroll
  for (int nd = 0; nd < 4; ++nd) {
    ushort4 o4;
    o4.x = f2b(acc[nd][0]); o4.y = f2b(acc[nd][1]);
    o4.z = f2b(acc[nd][2]); o4.w = f2b(acc[nd][3]);
    *(ushort4*)(partO + (size_t)bid * 4096 + qrow * 64 + nd * 16 + 4 * g) = o4;
  }
  if (g == 0) {
    partML[(size_t)bid * 128 + qrow * 2 + 0] = mstate;
    partML[(size_t)bid * 128 + qrow * 2 + 1] = lsum;
  }
}

// ---------------- combine: merge <=4 KV-chunk partials per q-tile ----------------
__global__ __launch_bounds__(256) void attn_combine(const unsigned short* __restrict__ partO,
                                                    const float* __restrict__ partML,
                                                    unsigned short* __restrict__ out) {
  const int bid = blockIdx.x;                      // 1024 = 32 qt x 32 bh
  const int qt = bid >> 5, bh = bid & 31;
  const int b = bh >> 4, h = bh & 15;
  const int np = (qt >> 3) + 1;                    // partials: ceil((qt+1)/8)
  const int t = threadIdx.x;
  const int row = t >> 2, cg = (t & 3) * 16;       // 64 rows x 4 col-groups of 16
  const float SCL = 0.18033688f;
  int slot0 = ((qt +  0) << 5) | bh;
  int slot1 = ((qt + 24) << 5) | bh;
  int slot2 = ((qt + 40) << 5) | bh;
  int slot3 = ((qt + 48) << 5) | bh;
  float mstar = partML[(size_t)slot0 * 128 + row * 2];
  if (np > 1) mstar = fmaxf(mstar, partML[(size_t)slot1 * 128 + row * 2]);
  if (np > 2) mstar = fmaxf(mstar, partML[(size_t)slot2 * 128 + row * 2]);
  if (np > 3) mstar = fmaxf(mstar, partML[(size_t)slot3 * 128 + row * 2]);
  float L = 0.f;
  float o[16];
  #pragma unroll
  for (int j = 0; j < 16; ++j) o[j] = 0.f;
  #pragma unroll
  for (int p = 0; p < 4; ++p) {
    if (p < np) {
      int slot = p == 0 ? slot0 : (p == 1 ? slot1 : (p == 2 ? slot2 : slot3));
      float mp = partML[(size_t)slot * 128 + row * 2 + 0];
      float lp = partML[(size_t)slot * 128 + row * 2 + 1];
      float wgt = exp2f((mp - mstar) * SCL);
      L = fmaf(wgt, lp, L);
      const unsigned short* src = partO + (size_t)slot * 4096 + row * 64 + cg;
      u16x8 a = *(const u16x8*)src;
      u16x8 bb = *(const u16x8*)(src + 8);
      #pragma unroll
      for (int j = 0; j < 8; ++j) {
        o[j]     = fmaf(b2f(a[j]),  wgt, o[j]);
        o[j + 8] = fmaf(b2f(bb[j]), wgt, o[j + 8]);
      }
    }
  }
  float rinv = 1.0f / L;
  u16x8 r0, r1;
  #pragma unroll
  for (int j = 0; j < 8; ++j) {
    r0[j] = f2b(o[j] * rinv);
    r1[j] = f2b(o[j + 8] * rinv);
  }
  size_t trow = (size_t)b * 2048 + qt * 64 + row;
  *(u16x8*)(out + trow * 1024 + h * 64 + cg) = r0;
  *(u16x8*)(out + trow * 1024 + h * 64 + cg + 8) = r1;
}

// ---------------- launch ----------------
extern "C" void kernel_launch(void* const* d_in, const int* in_sizes, int n_in,
                              void* d_out, int out_size, void* d_ws, size_t ws_size,
                              hipStream_t stream) {
  const float* x      = (const float*)d_in[0];
  const float* W_attn = (const float*)d_in[1];
  const float* b_attn = (const float*)d_in[2];
  const float* W_proj = (const float*)d_in[3];
  const float* b_proj = (const float*)d_in[4];
  float* out = (float*)d_out;

  char* ws = (char*)d_ws;
  unsigned short* Wproj_t  = (unsigned short*)(ws + 0);
  unsigned short* qkv      = (unsigned short*)(ws + 2097152);
  unsigned short* x_bf     = (unsigned short*)(ws + 27262976);
  unsigned short* Wattn_t  = (unsigned short*)(ws + 35651584);
  unsigned short* partO    = (unsigned short*)(ws + 27262976);   // overlaps x_bf/Wattn_t (dead)
  unsigned short* attn_out = (unsigned short*)(ws + 48234496);
  float*          partML   = (float*)(ws + 56623104);

  convert_f32_bf16<<<2048, 256, 0, stream>>>(x, x_bf, 4194304);
  transpose_f32_bf16<<<dim3(96, 32), dim3(32, 8), 0, stream>>>(W_attn, Wattn_t, 1024, 3072);
  transpose_f32_bf16<<<dim3(32, 32), dim3(32, 8), 0, stream>>>(W_proj, Wproj_t, 1024, 1024);

  gemm_bt<true><<<dim3(32, 24), 256, 0, stream>>>(x_bf, Wattn_t, b_attn, qkv, 4096, 3072, 1024);
  attn_kernel<<<2560, 256, 0, stream>>>(qkv, partO, partML);
  attn_combine<<<1024, 256, 0, stream>>>(partO, partML, attn_out);
  gemm_bt<false><<<dim3(32, 8), 256, 0, stream>>>(attn_out, Wproj_t, b_proj, out, 4096, 1024, 1024);
}